// Round 1
// baseline (41889.563 us; speedup 1.0000x reference)
//
#include <hip/hip_runtime.h>
#include <hip/hip_bf16.h>
#include <math.h>

#define T_LEN 512
#define NB    32
#define EMB_  41
#define IN0_  42
#define HID_  800
#define G4_   3200
#define IN1_  1600
#define NU    20

typedef unsigned short u16;
typedef unsigned int   u32;

__device__ __forceinline__ float bf2f(u16 v) {
    union { u32 u; float f; } c; c.u = ((u32)v) << 16; return c.f;
}
__device__ __forceinline__ u16 f2bf(float f) {
    union { float f; u32 u; } c; c.f = f;
    u32 r = (c.u + 0x7fffu + ((c.u >> 16) & 1u)) >> 16;
    return (u16)r;
}

// One 8-wide K chunk: 4 gate-rows (i,f,g,o of one hidden unit) x 4 batch lanes.
// src: bf16 activation slab, row stride rs elements; lanes sharing a row hit the
// same address (HW broadcast), so global reads stay cheap without LDS staging.
__device__ __forceinline__ void mac8(const u16* __restrict__ src, int rs, int bg,
                                     const float* __restrict__ w0, const float* __restrict__ w1,
                                     const float* __restrict__ w2, const float* __restrict__ w3,
                                     int k0, float acc[4][4])
{
    float xv[4][8];
#pragma unroll
    for (int i = 0; i < 4; ++i) {
        uint4 v = *(const uint4*)(src + (size_t)(bg + i*8)*rs + k0);
        union { u32 u; float f; } c;
        c.u = v.x << 16;         xv[i][0] = c.f;
        c.u = v.x & 0xffff0000u; xv[i][1] = c.f;
        c.u = v.y << 16;         xv[i][2] = c.f;
        c.u = v.y & 0xffff0000u; xv[i][3] = c.f;
        c.u = v.z << 16;         xv[i][4] = c.f;
        c.u = v.z & 0xffff0000u; xv[i][5] = c.f;
        c.u = v.w << 16;         xv[i][6] = c.f;
        c.u = v.w & 0xffff0000u; xv[i][7] = c.f;
    }
    const float* wp[4] = {w0, w1, w2, w3};
#pragma unroll
    for (int g = 0; g < 4; ++g) {
        float4 a = *(const float4*)(wp[g] + k0);
        float4 b = *(const float4*)(wp[g] + k0 + 4);
        float w[8] = {a.x,a.y,a.z,a.w,b.x,b.y,b.z,b.w};
#pragma unroll
        for (int kk = 0; kk < 8; ++kk)
#pragma unroll
            for (int i = 0; i < 4; ++i)
                acc[g][i] = fmaf(w[kk], xv[i][kk], acc[g][i]);
    }
}

// One LSTM time step, both directions, fused input+recurrent GEMM.
// grid = 200 blocks: dir(2) x 100 j-chunks of 8 hidden units; block = 256 threads.
// Thread (kr,jl,bg): K-split quarter kr, hidden unit j0+jl, batches {bg,bg+8,bg+16,bg+24},
// all 4 gates of that unit. Partials reduced through LDS, then 1 (j,b) update per thread.
template<int LAYER>
__global__ __launch_bounds__(256)
void lstm_step(const float* __restrict__ seq, const u16* __restrict__ xin,
               const float* __restrict__ w_ih, const float* __restrict__ w_hh,
               const float* __restrict__ bias,
               u16* __restrict__ hbuf, float* __restrict__ c_st,
               u16* __restrict__ hstore, int s)
{
    constexpr int KX = LAYER ? IN1_ : IN0_;
    __shared__ float part[4*8*4*NB];   // [kr][jl][gate][b] = 16 KB

    const int tid = threadIdx.x;
    const int d   = blockIdx.x / 100;
    const int jc  = blockIdx.x % 100;
    const int j0  = jc * 8;
    const int t   = d ? (T_LEN - 1 - s) : s;

    const u16* hb_cur = hbuf + (s & 1) * (2*NB*HID_);
    u16*       hb_nxt = hbuf + ((s & 1) ^ 1) * (2*NB*HID_);

    const int kr = tid >> 6;
    const int st = tid & 63;
    const int jl = st >> 3;
    const int bg = st & 7;
    const int j  = j0 + jl;

    float acc[4][4] = {};

    const float* wi0 = w_ih + (size_t)(d*G4_ + 0*HID_ + j) * KX;
    const float* wi1 = w_ih + (size_t)(d*G4_ + 1*HID_ + j) * KX;
    const float* wi2 = w_ih + (size_t)(d*G4_ + 2*HID_ + j) * KX;
    const float* wi3 = w_ih + (size_t)(d*G4_ + 3*HID_ + j) * KX;

    if (LAYER == 0) {
        // x part: fp32 seq, scalar loop over k<41. Position feature (k=41) is handled
        // EXACTLY in the update phase (t * w[:,41]) to avoid bf16-rounding t.
        const float* xs = seq + (size_t)t*NB*EMB_;
        const int kb = (kr*41)/4, ke = ((kr+1)*41)/4;
        for (int k = kb; k < ke; ++k) {
            float w0 = wi0[k], w1 = wi1[k], w2 = wi2[k], w3 = wi3[k];
#pragma unroll
            for (int i = 0; i < 4; ++i) {
                float x = xs[(bg + i*8)*EMB_ + k];
                acc[0][i] = fmaf(w0, x, acc[0][i]);
                acc[1][i] = fmaf(w1, x, acc[1][i]);
                acc[2][i] = fmaf(w2, x, acc[2][i]);
                acc[3][i] = fmaf(w3, x, acc[3][i]);
            }
        }
    } else {
        // x part: bf16 h0[t] slab, 8-wide chunks; kr quarter = 50 chunks of 1600
        const u16* xs = xin + (size_t)t*NB*IN1_;
        for (int kc = kr*50; kc < kr*50 + 50; ++kc)
            mac8(xs, IN1_, bg, wi0, wi1, wi2, wi3, kc*8, acc);
    }
    {
        // h part: bf16 recurrent state, kr quarter = 25 chunks of 800
        const u16* hs = hb_cur + (size_t)d*NB*HID_;
        const float* wh0 = w_hh + (size_t)(d*G4_ + 0*HID_ + j) * HID_;
        const float* wh1 = w_hh + (size_t)(d*G4_ + 1*HID_ + j) * HID_;
        const float* wh2 = w_hh + (size_t)(d*G4_ + 2*HID_ + j) * HID_;
        const float* wh3 = w_hh + (size_t)(d*G4_ + 3*HID_ + j) * HID_;
        for (int kc = kr*25; kc < kr*25 + 25; ++kc)
            mac8(hs, HID_, bg, wh0, wh1, wh2, wh3, kc*8, acc);
    }

#pragma unroll
    for (int g = 0; g < 4; ++g)
#pragma unroll
        for (int i = 0; i < 4; ++i)
            part[((kr*8 + jl)*4 + g)*NB + bg + i*8] = acc[g][i];
    __syncthreads();

    // update: one (hidden unit, batch) per thread; fp32 gates/cell state
    {
        const int ujl = tid >> 5;
        const int b   = tid & 31;
        const int uj  = j0 + ujl;
        float v[4];
#pragma unroll
        for (int g = 0; g < 4; ++g) {
            float x = bias[d*G4_ + g*HID_ + uj];
            if (LAYER == 0)
                x += (float)t * w_ih[(size_t)(d*G4_ + g*HID_ + uj)*IN0_ + (IN0_-1)];
#pragma unroll
            for (int q = 0; q < 4; ++q)
                x += part[((q*8 + ujl)*4 + g)*NB + b];
            v[g] = x;
        }
        float ig = 1.f/(1.f + expf(-v[0]));
        float fg = 1.f/(1.f + expf(-v[1]));
        float gg = tanhf(v[2]);
        float og = 1.f/(1.f + expf(-v[3]));
        float* cp = c_st + (size_t)(d*NB + b)*HID_ + uj;
        float cn = fg * (*cp) + ig * gg;
        *cp = cn;
        float hn = og * tanhf(cn);
        u16 hb = f2bf(hn);
        hb_nxt[(d*NB + b)*HID_ + uj] = hb;
        // concat([fwd, bwd], -1) at natural time t
        hstore[(size_t)(t*NB + b)*IN1_ + d*HID_ + uj] = hb;
    }
}

// linear -> softmax -> alphabet sin/cos mix. Stores (cosP, sinP) directly:
// pred_coords consumes P only via cos/sin, so skip atan2 + re-sincos entirely.
__global__ __launch_bounds__(64)
void epilogue(const u16* __restrict__ h1, const float* __restrict__ lin_w,
              const float* __restrict__ lin_b, const float* __restrict__ alphabet,
              float* __restrict__ cs)
{
    __shared__ float lh[IN1_];
    __shared__ float logits[NU];
    __shared__ float soft[NU];
    const int row = blockIdx.x;            // t*NB + b
    const int tid = threadIdx.x;
    const u16* hr = h1 + (size_t)row * IN1_;
    for (int k = tid; k < IN1_; k += 64) lh[k] = bf2f(hr[k]);
    __syncthreads();
    if (tid < NU) {
        float a = lin_b[tid];
        const float* wr = lin_w + tid*IN1_;
        for (int k = 0; k < IN1_; k += 4) {
            float4 w4 = *(const float4*)(wr + k);
            a += lh[k]*w4.x + lh[k+1]*w4.y + lh[k+2]*w4.z + lh[k+3]*w4.w;
        }
        logits[tid] = a;
    }
    __syncthreads();
    if (tid < NU) {
        float m = -1e30f;
        for (int u = 0; u < NU; ++u) m = fmaxf(m, logits[u]);
        float ssum = 0.f;
        for (int u = 0; u < NU; ++u) ssum += expf(logits[u] - m);
        soft[tid] = expf(logits[tid] - m) / ssum;
    }
    __syncthreads();
    if (tid < 3) {
        float sv = 0.f, cv = 0.f;
        for (int u = 0; u < NU; ++u) {
            float al = alphabet[u*3 + tid];
            sv += soft[u] * sinf(al);
            cv += soft[u] * cosf(al);
        }
        float rinv = rsqrtf(fmaxf(sv*sv + cv*cv, 1e-30f));
        *(float2*)(cs + ((size_t)row*3 + tid)*2) = make_float2(cv*rinv, sv*rinv);
    }
}

// Sequential chain extension: one lane per molecule, 511 steps x 3 atoms.
__global__ __launch_bounds__(64)
void geometry(const float* __restrict__ cs, float* __restrict__ out)
{
    const int b = threadIdx.x;
    if (b >= NB) return;
    const float blen[3] = {1.329f, 1.459f, 1.525f};
    const float bang[3] = {2.034f, 2.119f, 1.937f};
    float sT[3], cT[3];
#pragma unroll
    for (int i = 0; i < 3; ++i) { sT[i] = sinf(bang[i]); cT[i] = cosf(bang[i]); }

    float Ax=0.f,Ay=0.f,Az=1.f, Bx=0.f,By=1.f,Bz=0.f, Cx=1.f,Cy=0.f,Cz=0.f;
    out[(0*NB + b)*3 + 0] = 0.f; out[(0*NB + b)*3 + 1] = 0.f; out[(0*NB + b)*3 + 2] = 1.f;
    out[(1*NB + b)*3 + 0] = 0.f; out[(1*NB + b)*3 + 1] = 1.f; out[(1*NB + b)*3 + 2] = 0.f;
    out[(2*NB + b)*3 + 0] = 1.f; out[(2*NB + b)*3 + 1] = 0.f; out[(2*NB + b)*3 + 2] = 0.f;

    for (int t = 1; t < T_LEN; ++t) {
        float2 pc[3];
#pragma unroll
        for (int i = 0; i < 3; ++i)
            pc[i] = *(const float2*)(cs + (((size_t)t*NB + b)*3 + i)*2);
#pragma unroll
        for (int i = 0; i < 3; ++i) {
            float R = blen[i];
            float d2x = -R*cT[i], d2y = R*pc[i].x*sT[i], d2z = R*pc[i].y*sT[i];
            float bcx = Cx-Bx, bcy = Cy-By, bcz = Cz-Bz;
            float inv = rsqrtf(bcx*bcx + bcy*bcy + bcz*bcz);
            bcx *= inv; bcy *= inv; bcz *= inv;
            float abx = Bx-Ax, aby = By-Ay, abz = Bz-Az;
            float nx = aby*bcz - abz*bcy;
            float ny = abz*bcx - abx*bcz;
            float nz = abx*bcy - aby*bcx;
            inv = rsqrtf(fmaxf(nx*nx + ny*ny + nz*nz, 1e-30f));
            nx *= inv; ny *= inv; nz *= inv;
            float mx = ny*bcz - nz*bcy;     // cross(n, bc)
            float my = nz*bcx - nx*bcz;
            float mz = nx*bcy - ny*bcx;
            float Dx = bcx*d2x + mx*d2y + nx*d2z + Cx;
            float Dy = bcy*d2x + my*d2y + ny*d2z + Cy;
            float Dz = bcz*d2x + mz*d2y + nz*d2z + Cz;
            Ax=Bx; Ay=By; Az=Bz; Bx=Cx; By=Cy; Bz=Cz; Cx=Dx; Cy=Dy; Cz=Dz;
            const int r = 3 + (t-1)*3 + i;
            out[((size_t)r*NB + b)*3 + 0] = Dx;
            out[((size_t)r*NB + b)*3 + 1] = Dy;
            out[((size_t)r*NB + b)*3 + 2] = Dz;
        }
    }
}

extern "C" void kernel_launch(void* const* d_in, const int* in_sizes, int n_in,
                              void* d_out, int out_size, void* d_ws, size_t ws_size,
                              hipStream_t stream)
{
    (void)in_sizes; (void)n_in; (void)out_size; (void)ws_size;
    const float* seq   = (const float*)d_in[0];
    // d_in[1] = lengths: unused by the reference (all MAX_LEN, no masking)
    const float* w_ih0 = (const float*)d_in[2];
    const float* w_hh0 = (const float*)d_in[3];
    const float* b0    = (const float*)d_in[4];
    const float* w_ih1 = (const float*)d_in[5];
    const float* w_hh1 = (const float*)d_in[6];
    const float* b1    = (const float*)d_in[7];
    const float* lin_w = (const float*)d_in[8];
    const float* lin_b = (const float*)d_in[9];
    const float* alpha = (const float*)d_in[10];

    char* ws = (char*)d_ws;
    size_t off = 0;
    u16* h0 = (u16*)(ws + off);    off += (size_t)T_LEN*NB*IN1_*2;   // 52,428,800
    u16* h1 = (u16*)(ws + off);    off += (size_t)T_LEN*NB*IN1_*2;   // 52,428,800
    u16* hbuf = (u16*)(ws + off);  off += (size_t)2*2*NB*HID_*2;     // 204,800 (double buf x dir)
    float* c_st = (float*)(ws + off); off += (size_t)2*NB*HID_*4;    // 204,800
    float* cs = (float*)(ws + off);   off += (size_t)T_LEN*NB*3*2*4; // 393,216
    // total ~100.8 MiB of workspace

    const size_t state_bytes = (size_t)2*2*NB*HID_*2 + (size_t)2*NB*HID_*4; // hbuf + c (contiguous)

    hipMemsetAsync(hbuf, 0, state_bytes, stream);
    for (int s = 0; s < T_LEN; ++s)
        lstm_step<0><<<dim3(200), dim3(256), 0, stream>>>(seq, (const u16*)nullptr,
            w_ih0, w_hh0, b0, hbuf, c_st, h0, s);

    hipMemsetAsync(hbuf, 0, state_bytes, stream);
    for (int s = 0; s < T_LEN; ++s)
        lstm_step<1><<<dim3(200), dim3(256), 0, stream>>>((const float*)nullptr, h0,
            w_ih1, w_hh1, b1, hbuf, c_st, h1, s);

    epilogue<<<dim3(T_LEN*NB), dim3(64), 0, stream>>>(h1, lin_w, lin_b, alpha, cs);
    geometry<<<dim3(1), dim3(64), 0, stream>>>(cs, (float*)d_out);
}

// Round 3
// 18197.914 us; speedup vs baseline: 2.3019x; 2.3019x over previous
//
#include <hip/hip_runtime.h>
#include <math.h>

#define T_LEN 512
#define NB    32
#define EMB_  41
#define IN0_  42
#define HID_  800
#define G4_   3200
#define IN1_  1600
#define NU    20

typedef unsigned short u16;
typedef unsigned int   u32;
typedef __attribute__((ext_vector_type(8))) short short8;
typedef __attribute__((ext_vector_type(4))) float f32x4;

__device__ __forceinline__ float bf2f(u16 v) {
    union { u32 u; float f; } c; c.u = ((u32)v) << 16; return c.f;
}
__device__ __forceinline__ u16 f2bf(float f) {
    union { float f; u32 u; } c; c.f = f;
    u32 r = (c.u + 0x7fffu + ((c.u >> 16) & 1u)) >> 16;
    return (u16)r;
}
__device__ __forceinline__ f32x4 mfma16(short8 a, short8 b, f32x4 c) {
    return __builtin_amdgcn_mfma_f32_16x16x32_bf16(a, b, c, 0, 0, 0);
}

// ---- weight prep: w_hh -> bf16 hi/lo pairs in MFMA A-frag order ----
// layout: [d(2)][ch(100)][pair(2)][hl(2)][kc(25)][lane(64)][i(8)]
// element: A[m=lane&15][k=kc*32+(lane>>4)*8+i], m -> gate g=pair*2+(m>>3), unit j=ch*8+(m&7)
__global__ __launch_bounds__(256) void prep_whh(const float* __restrict__ whh, u16* __restrict__ out)
{
    int idx = blockIdx.x * 256 + threadIdx.x;          // < 10,240,000
    int i = idx & 7;
    int l = (idx >> 3) & 63;
    int rest = idx >> 9;                                // (((d*100+ch)*2+p)*2+hl)*25 + kc
    int kc = rest % 25; rest /= 25;
    int hl = rest & 1;  rest >>= 1;
    int p  = rest & 1;  rest >>= 1;
    int ch = rest % 100;
    int d  = rest / 100;
    int m = l & 15, gp = m >> 3, ju = m & 7;
    int g = p*2 + gp, j = ch*8 + ju;
    int k = kc*32 + (l >> 4)*8 + i;
    float w = whh[((size_t)(d*G4_ + g*HID_ + j))*HID_ + k];
    u16 hi = f2bf(w);
    out[idx] = hl ? f2bf(w - bf2f(hi)) : hi;
}

// ---- w_ih1 -> plain bf16 A-frags, block-local grouping like prep_whh ----
// layout: [d(2)][ch(100)][pair(2)][kc(50)][lane(64)][i(8)]
__global__ __launch_bounds__(256) void prep_wih1(const float* __restrict__ wih, u16* __restrict__ out)
{
    int idx = blockIdx.x * 256 + threadIdx.x;          // < 10,240,000
    int i = idx & 7;
    int l = (idx >> 3) & 63;
    int rest = idx >> 9;                                // ((d*100+ch)*2+p)*50 + kc
    int kc = rest % 50; rest /= 50;
    int p  = rest & 1;  rest >>= 1;
    int ch = rest % 100;
    int d  = rest / 100;
    int m = l & 15;
    int g = p*2 + (m >> 3), j = ch*8 + (m & 7);
    int k = kc*32 + (l >> 4)*8 + i;
    out[idx] = f2bf(wih[((size_t)(d*G4_ + g*HID_ + j))*IN1_ + k]);
}

__global__ __launch_bounds__(256) void logits_init(const float* __restrict__ lb, float* __restrict__ logits)
{
    int idx = blockIdx.x * 256 + threadIdx.x;
    if (idx < T_LEN*NB*NU) logits[idx] = lb[idx % NU];
}

// ---- one LSTM time step, both dirs. MFMA h-GEMM (hi/lo weights); LAYER 1 also
// fuses the x-GEMM (w_ih1 frags x h0f B-frags, hl waves split K) and the final
// linear (per-block LDS reduce -> global fp32 atomics into logits).
// grid 200: bid = d*100 + ch(8 units). 4 waves: (pair p, hilo hl).
// h state in B-frag order per dir: [kc(25)][nt(2)][lane(64)][i(8)] (25600 u16/dir).
template<int LAYER>
__global__ __launch_bounds__(256)
void lstm_step(const float* __restrict__ seq, const float* __restrict__ wih0,
               const u16* __restrict__ wihA, const u16* __restrict__ whhA,
               const float* __restrict__ bias, const float* __restrict__ lin_w,
               u16* __restrict__ hB, float* __restrict__ c_st,
               u16* __restrict__ h0out, float* __restrict__ logits, int s)
{
    __shared__ float part[2*2*2*16*16];   // [p][hl][nt][m][n] = 8 KB
    __shared__ float lacc[NB*NU];         // [b][u] logit partials, 2.5 KB
    __shared__ float lwcol[8*NU];         // lin_w columns for this block's 8 units

    const int tid = threadIdx.x;
    const int d  = blockIdx.x / 100;
    const int ch = blockIdx.x % 100;
    const int t  = d ? (T_LEN - 1 - s) : s;

    const u16* hcur = hB + (s & 1) * (2*25600) + d*25600;
    u16*       hnxt = hB + ((s & 1) ^ 1) * (2*25600) + d*25600;

    const int w = tid >> 6, l = tid & 63;
    const int p = w & 1, hl = w >> 1;

    f32x4 acc0 = {0.f,0.f,0.f,0.f}, acc1 = {0.f,0.f,0.f,0.f};

    // recurrent part: 25 kc chunks of K=800, A = hi (hl=0) or lo (hl=1)
    {
        const u16* A = whhA + ((size_t)(((d*100 + ch)*2 + p)*2 + hl)*25) * 512;
#pragma unroll 5
        for (int kc = 0; kc < 25; ++kc) {
            short8 a  = *(const short8*)(A + kc*512 + l*8);
            short8 b0 = *(const short8*)(hcur + (kc*2 + 0)*512 + l*8);
            short8 b1 = *(const short8*)(hcur + (kc*2 + 1)*512 + l*8);
            acc0 = mfma16(a, b0, acc0);
            acc1 = mfma16(a, b1, acc1);
        }
    }
    if (LAYER == 1) {
        // x part: K=1600 split across hl waves (25 kc each); B = h0f[t] slab
        const u16* XA = wihA + ((size_t)((d*100 + ch)*2 + p)) * (50*512);
        const u16* xb = h0out + (size_t)t * 51200;   // h0f (read-only here)
#pragma unroll 5
        for (int kc = hl*25; kc < hl*25 + 25; ++kc) {
            short8 a  = *(const short8*)(XA + kc*512 + l*8);
            short8 b0 = *(const short8*)(xb + (kc*2 + 0)*512 + l*8);
            short8 b1 = *(const short8*)(xb + (kc*2 + 1)*512 + l*8);
            acc0 = mfma16(a, b0, acc0);
            acc1 = mfma16(a, b1, acc1);
        }
    }
    {
        const int mrow = (l >> 4)*4, n = l & 15;
#pragma unroll
        for (int r = 0; r < 4; ++r) {
            part[(((p*2 + hl)*2 + 0)*16 + mrow + r)*16 + n] = acc0[r];
            part[(((p*2 + hl)*2 + 1)*16 + mrow + r)*16 + n] = acc1[r];
        }
    }
    if (LAYER == 1) {
        for (int k = tid; k < NB*NU; k += 256) lacc[k] = 0.f;
        if (tid < 8*NU) {
            int ju = tid / NU, u = tid % NU;
            lwcol[tid] = lin_w[(size_t)u*IN1_ + d*HID_ + ch*8 + ju];
        }
    }
    __syncthreads();

    // update: thread (ju, b); gate rows m=(g&1)*8+ju of pair g>>1
    const int ju = tid >> 5, b = tid & 31;
    const int j  = ch*8 + ju;
    const int nt = b >> 4, n = b & 15;
    float v[4];
#pragma unroll
    for (int g = 0; g < 4; ++g) {
        const int pp = g >> 1, m = (g & 1)*8 + ju;
        float x = part[(((pp*2 + 0)*2 + nt)*16 + m)*16 + n]
                + part[(((pp*2 + 1)*2 + nt)*16 + m)*16 + n];
        x += bias[d*G4_ + g*HID_ + j];
        if (LAYER == 0) {
            const float* wr = wih0 + ((size_t)(d*G4_ + g*HID_ + j))*IN0_;
            const float* xr = seq + ((size_t)t*NB + b)*EMB_;
            float dot = (float)t * wr[EMB_];       // exact position feature
            for (int k = 0; k < EMB_; ++k) dot = fmaf(wr[k], xr[k], dot);
            x += dot;
        }
        v[g] = x;
    }
    float ig = 1.f/(1.f + expf(-v[0]));
    float fg = 1.f/(1.f + expf(-v[1]));
    float gg = tanhf(v[2]);
    float og = 1.f/(1.f + expf(-v[3]));
    float* cp = c_st + (size_t)(d*NB + b)*HID_ + j;
    float cn = fg * (*cp) + ig * gg;
    *cp = cn;
    float hn = og * tanhf(cn);
    u16 hb = f2bf(hn);

    // scatter h into next step's B-frag slot (k = j)
    {
        int kc2 = j >> 5, wi = j & 31;
        int ll = ((wi >> 3) << 4) | n, ii = wi & 7;
        hnxt[(kc2*2 + nt)*512 + ll*8 + ii] = hb;
    }
    if (LAYER == 0) {
        // h0 in GEMM B-frag order: [t][kc(50)][nt][lane][i], k = d*800 + j
        int k0 = d*HID_ + j;
        int kc2 = k0 >> 5, wi = k0 & 31;
        int ll = ((wi >> 3) << 4) | n, ii = wi & 7;
        h0out[(size_t)t*51200 + (kc2*2 + nt)*512 + ll*8 + ii] = hb;
    } else {
        // fused final linear: this block's 8 units contribute to logits[t][b][:]
#pragma unroll 4
        for (int u = 0; u < NU; ++u)
            atomicAdd(&lacc[b*NU + u], lwcol[ju*NU + u] * hn);
        __syncthreads();
        for (int k = tid; k < NB*NU; k += 256)
            atomicAdd(logits + (size_t)t*(NB*NU) + k, lacc[k]);
    }
}

// ---- softmax over 20 logits -> alphabet sin/cos mix; store (cosP, sinP) ----
__global__ __launch_bounds__(256)
void epilogue(const float* __restrict__ logits, const float* __restrict__ alphabet,
              float* __restrict__ cs)
{
    __shared__ float sa[NU*3], ca[NU*3];
    const int tid = threadIdx.x;
    if (tid < NU*3) {
        float al = alphabet[tid];
        sa[tid] = sinf(al); ca[tid] = cosf(al);
    }
    __syncthreads();
    const int row = blockIdx.x * 256 + tid;   // t*NB + b
    if (row >= T_LEN*NB) return;
    float lg[NU];
    float m = -1e30f;
#pragma unroll 4
    for (int u = 0; u < NU; ++u) { lg[u] = logits[(size_t)row*NU + u]; m = fmaxf(m, lg[u]); }
    float ssum = 0.f;
#pragma unroll 4
    for (int u = 0; u < NU; ++u) { lg[u] = expf(lg[u] - m); ssum += lg[u]; }
    float inv = 1.f / ssum;
#pragma unroll
    for (int i = 0; i < 3; ++i) {
        float sv = 0.f, cv = 0.f;
#pragma unroll 4
        for (int u = 0; u < NU; ++u) {
            float sw = lg[u] * inv;
            sv += sw * sa[u*3 + i];
            cv += sw * ca[u*3 + i];
        }
        float rinv = rsqrtf(fmaxf(sv*sv + cv*cv, 1e-30f));
        *(float2*)(cs + ((size_t)row*3 + i)*2) = make_float2(cv*rinv, sv*rinv);
    }
}

// ---- sequential chain extension: one lane per molecule ----
__global__ __launch_bounds__(64)
void geometry(const float* __restrict__ cs, float* __restrict__ out)
{
    const int b = threadIdx.x;
    if (b >= NB) return;
    const float blen[3] = {1.329f, 1.459f, 1.525f};
    const float bang[3] = {2.034f, 2.119f, 1.937f};
    float sT[3], cT[3];
#pragma unroll
    for (int i = 0; i < 3; ++i) { sT[i] = sinf(bang[i]); cT[i] = cosf(bang[i]); }

    float Ax=0.f,Ay=0.f,Az=1.f, Bx=0.f,By=1.f,Bz=0.f, Cx=1.f,Cy=0.f,Cz=0.f;
    out[(0*NB + b)*3 + 0] = 0.f; out[(0*NB + b)*3 + 1] = 0.f; out[(0*NB + b)*3 + 2] = 1.f;
    out[(1*NB + b)*3 + 0] = 0.f; out[(1*NB + b)*3 + 1] = 1.f; out[(1*NB + b)*3 + 2] = 0.f;
    out[(2*NB + b)*3 + 0] = 1.f; out[(2*NB + b)*3 + 1] = 0.f; out[(2*NB + b)*3 + 2] = 0.f;

    for (int t = 1; t < T_LEN; ++t) {
        float2 pc[3];
#pragma unroll
        for (int i = 0; i < 3; ++i)
            pc[i] = *(const float2*)(cs + (((size_t)t*NB + b)*3 + i)*2);
#pragma unroll
        for (int i = 0; i < 3; ++i) {
            float R = blen[i];
            float d2x = -R*cT[i], d2y = R*pc[i].x*sT[i], d2z = R*pc[i].y*sT[i];
            float bcx = Cx-Bx, bcy = Cy-By, bcz = Cz-Bz;
            float inv = rsqrtf(bcx*bcx + bcy*bcy + bcz*bcz);
            bcx *= inv; bcy *= inv; bcz *= inv;
            float abx = Bx-Ax, aby = By-Ay, abz = Bz-Az;
            float nx = aby*bcz - abz*bcy;
            float ny = abz*bcx - abx*bcz;
            float nz = abx*bcy - aby*bcx;
            inv = rsqrtf(fmaxf(nx*nx + ny*ny + nz*nz, 1e-30f));
            nx *= inv; ny *= inv; nz *= inv;
            float mx = ny*bcz - nz*bcy;
            float my = nz*bcx - nx*bcz;
            float mz = nx*bcy - ny*bcx;
            float Dx = bcx*d2x + mx*d2y + nx*d2z + Cx;
            float Dy = bcy*d2x + my*d2y + ny*d2z + Cy;
            float Dz = bcz*d2x + mz*d2y + nz*d2z + Cz;
            Ax=Bx; Ay=By; Az=Bz; Bx=Cx; By=Cy; Bz=Cz; Cx=Dx; Cy=Dy; Cz=Dz;
            const int r = 3 + (t-1)*3 + i;
            out[((size_t)r*NB + b)*3 + 0] = Dx;
            out[((size_t)r*NB + b)*3 + 1] = Dy;
            out[((size_t)r*NB + b)*3 + 2] = Dz;
        }
    }
}

extern "C" void kernel_launch(void* const* d_in, const int* in_sizes, int n_in,
                              void* d_out, int out_size, void* d_ws, size_t ws_size,
                              hipStream_t stream)
{
    (void)in_sizes; (void)n_in; (void)out_size; (void)ws_size;
    const float* seq   = (const float*)d_in[0];
    const float* w_ih0 = (const float*)d_in[2];
    const float* w_hh0 = (const float*)d_in[3];
    const float* b0    = (const float*)d_in[4];
    const float* w_ih1 = (const float*)d_in[5];
    const float* w_hh1 = (const float*)d_in[6];
    const float* b1    = (const float*)d_in[7];
    const float* lin_w = (const float*)d_in[8];
    const float* lin_b = (const float*)d_in[9];
    const float* alpha = (const float*)d_in[10];

    // workspace: 95.5 MB total (round-1's 100.8 MB is known to fit)
    char* ws = (char*)d_ws;
    size_t off = 0;
    u16* h0f    = (u16*)(ws + off); off += 52428800ull;  // [t][kc50][nt2][lane][i] bf16
    u16* wA0    = (u16*)(ws + off); off += 20480000ull;  // whh0 hi/lo frags, then w_ih1 frags
    u16* whhA1  = (u16*)(ws + off); off += 20480000ull;  // whh1 hi/lo frags
    float* logits = (float*)(ws + off); off += 1310720ull; // [t][b][u] fp32
    u16* hB     = (u16*)(ws + off); off += 204800ull;    // 2 bufs x 2 dirs x 25600
    float* c_st = (float*)(ws + off); off += 204800ull;
    float* cs   = (float*)(ws + off); off += 393216ull;

    prep_whh<<<dim3(40000), dim3(256), 0, stream>>>(w_hh0, wA0);
    prep_whh<<<dim3(40000), dim3(256), 0, stream>>>(w_hh1, whhA1);
    logits_init<<<dim3(1280), dim3(256), 0, stream>>>(lin_b, logits);

    hipMemsetAsync(hB, 0, 204800 + 204800, stream);   // hB + c_st contiguous
    for (int s = 0; s < T_LEN; ++s)
        lstm_step<0><<<dim3(200), dim3(256), 0, stream>>>(
            seq, w_ih0, (const u16*)nullptr, wA0, b0, (const float*)nullptr,
            hB, c_st, h0f, (float*)nullptr, s);

    prep_wih1<<<dim3(40000), dim3(256), 0, stream>>>(w_ih1, wA0);  // reuse wA0

    hipMemsetAsync(hB, 0, 204800 + 204800, stream);
    for (int s = 0; s < T_LEN; ++s)
        lstm_step<1><<<dim3(200), dim3(256), 0, stream>>>(
            (const float*)nullptr, (const float*)nullptr, wA0, whhA1, b1, lin_w,
            hB, c_st, h0f, logits, s);

    epilogue<<<dim3((T_LEN*NB + 255)/256), dim3(256), 0, stream>>>(logits, alpha, cs);
    geometry<<<dim3(1), dim3(64), 0, stream>>>(cs, (float*)d_out);
}